// Round 3
// baseline (889.472 us; speedup 1.0000x reference)
//
#include <hip/hip_runtime.h>
#include <hip/hip_bf16.h>
#include <cstdint>

typedef __bf16 bf16x8 __attribute__((ext_vector_type(8)));
typedef float  f32x4  __attribute__((ext_vector_type(4)));

__device__ __forceinline__ short f2b(float f) {
    union { float f; uint32_t u; } c{f};
    uint32_t u = c.u;
    uint32_t r = (u + 0x7FFFu + ((u >> 16) & 1u)) >> 16;
    return (short)(uint16_t)r;
}
__device__ __forceinline__ float b2f(short s) {
    return __uint_as_float(((uint32_t)(uint16_t)s) << 16);
}
__device__ __forceinline__ float wred(float v) {
    #pragma unroll
    for (int o = 32; o > 0; o >>= 1) v += __shfl_xor(v, o);
    return v;
}
// async global->LDS, 16B per lane; lds dest must be wave-uniform base.
__device__ __forceinline__ void g2l16(const void* g, void* l) {
    __builtin_amdgcn_global_load_lds(
        (const __attribute__((address_space(1))) void*)(uintptr_t)g,
        (__attribute__((address_space(3))) void*)(uint32_t)(uintptr_t)l,
        16, 0, 0);
}

// ---------------- small prep kernels ----------------

__global__ __launch_bounds__(256) void f2b_kernel(const float* __restrict__ in,
                                                  short* __restrict__ out, int n) {
    int i = blockIdx.x * 256 + threadIdx.x;
    if (i < n) out[i] = f2b(in[i]);
}

__global__ __launch_bounds__(256) void zerof(float* __restrict__ p, int n) {
    int i = blockIdx.x * 256 + threadIdx.x;
    if (i < n) p[i] = 0.f;
}

// one wave per item row: normalize item, dot vs 4 normalized protos, softmax -> cates
__global__ __launch_bounds__(256)
void items_cates(const float* __restrict__ emb, const float* __restrict__ proto,
                 short* __restrict__ items_b, float* __restrict__ cates, int N) {
    int w = threadIdx.x >> 6, lane = threadIdx.x & 63;
    int n = blockIdx.x * 4 + w;
    if (n >= N) return;
    float p0 = proto[lane], p1 = proto[64 + lane], p2 = proto[128 + lane], p3 = proto[192 + lane];
    float s0 = wred(p0 * p0); p0 /= fmaxf(sqrtf(s0), 1e-12f);
    float s1 = wred(p1 * p1); p1 /= fmaxf(sqrtf(s1), 1e-12f);
    float s2 = wred(p2 * p2); p2 /= fmaxf(sqrtf(s2), 1e-12f);
    float s3 = wred(p3 * p3); p3 /= fmaxf(sqrtf(s3), 1e-12f);
    float x = emb[(size_t)n * 64 + lane];
    float sx = wred(x * x);
    float xi = x / fmaxf(sqrtf(sx), 1e-12f);
    items_b[(size_t)n * 64 + lane] = f2b(xi);
    float d0 = wred(xi * p0), d1 = wred(xi * p1), d2 = wred(xi * p2), d3 = wred(xi * p3);
    float m = fmaxf(fmaxf(d0, d1), fmaxf(d2, d3));
    float e0 = __expf(d0 - m), e1 = __expf(d1 - m), e2 = __expf(d2 - m), e3 = __expf(d3 - m);
    float inv = 1.0f / (e0 + e1 + e2 + e3);
    float cv = (lane == 0) ? e0 : (lane == 1) ? e1 : (lane == 2) ? e2 : e3;
    if (lane < 4) cates[(size_t)n * 4 + lane] = cv * inv;
}

// one block per (k,b) row: xk = l2norm_over_n(x[b,:]*cates[:,k]) -> bf16
__global__ __launch_bounds__(256)
void xk_kernel(const float* __restrict__ x, const float* __restrict__ cates,
               short* __restrict__ out, int N) {
    __shared__ float red[4];
    int kb = blockIdx.x, k = kb >> 7, b = kb & 127;
    int tid = threadIdx.x, w = tid >> 6, lane = tid & 63;
    const float* xr = x + (size_t)b * N;
    float ss = 0.f;
    for (int i = tid; i < N; i += 256) {
        float v = xr[i] * cates[(size_t)i * 4 + k];
        ss += v * v;
    }
    ss = wred(ss);
    if (lane == 0) red[w] = ss;
    __syncthreads();
    float tot = red[0] + red[1] + red[2] + red[3];
    float inv = 1.0f / fmaxf(sqrtf(tot), 1e-12f);
    for (int i = tid; i < N; i += 256)
        out[(size_t)kb * N + i] = f2b(xr[i] * cates[(size_t)i * 4 + k] * inv);
}

// AdjT[j][i] = Adj[i][j], fp32 -> bf16, 64x64 tiles through LDS
__global__ __launch_bounds__(256)
void transpose_bf16(const float* __restrict__ A, short* __restrict__ At, int Nd) {
    __shared__ float t[64][65];
    int i0 = blockIdx.x * 64, j0 = blockIdx.y * 64;
    int tid = threadIdx.x;
    #pragma unroll
    for (int p = 0; p < 4; ++p) {
        int idx = p * 256 + tid;
        int r = idx >> 4, c4 = (idx & 15) * 4;
        const float4 v = *(const float4*)(A + (size_t)(i0 + r) * Nd + j0 + c4);
        t[r][c4] = v.x; t[r][c4 + 1] = v.y; t[r][c4 + 2] = v.z; t[r][c4 + 3] = v.w;
    }
    __syncthreads();
    #pragma unroll
    for (int p = 0; p < 8; ++p) {
        int idx = p * 256 + tid;
        int r = idx >> 5, c2 = (idx & 31) * 2;
        uint32_t lo = (uint32_t)(uint16_t)f2b(t[c2][r]);
        uint32_t hi = (uint32_t)(uint16_t)f2b(t[c2 + 1][r]);
        *(uint32_t*)(At + (size_t)(j0 + r) * Nd + i0 + c2) = lo | (hi << 16);
    }
}

// mu = l2norm(h[:64]+b), logvar = -(h[64:]+b); also write Z'[(b*4+k)][e] bf16 for decode
__global__ __launch_bounds__(128)
void mu_logvar(const float* __restrict__ hcf, const float* __restrict__ htxt,
               const float* __restrict__ bcf, const float* __restrict__ btxt,
               float* __restrict__ mu_cf, float* __restrict__ lv_cf,
               float* __restrict__ mu_t, float* __restrict__ lv_t,
               short* __restrict__ zcf, short* __restrict__ ztxt) {
    int r = blockIdx.x & 511;
    bool txt = blockIdx.x >= 512;
    const float* h = txt ? htxt : hcf;
    const float* bias = txt ? btxt : bcf;
    float* muo = txt ? mu_t : mu_cf;
    float* lvo = txt ? lv_t : lv_cf;
    short* z = txt ? ztxt : zcf;
    int t = threadIdx.x;
    float v = h[(size_t)r * 128 + t] + bias[t];
    if (t < 64) {
        float ss = wred(v * v);
        float mu = v / fmaxf(sqrtf(ss), 1e-12f);
        muo[(size_t)r * 64 + t] = mu;
        int k = r >> 7, b = r & 127;
        z[((size_t)b * 4 + k) * 64 + t] = f2b(mu);
    } else {
        lvo[(size_t)r * 64 + (t - 64)] = -v;
    }
}

// ---------------- BT-GEMM: C[m][n] = sum_k A[m][k]*B[n][k], bf16 MFMA ----------------
// BM=64, BN=128, BK=64; 4 waves (2x2), each 32x64 (2x4 fragments of 16x16x32).
// MODE 0: store bf16. MODE 1: store bf16 of (acc+X)*0.5. MODE 2: atomicAdd f32 (split-K).
// MODE 3: decode epilogue: rows are b*4+k; out[b][n] = log(sum_j exp(acc[j])*cates[n][j]).
template <int MODE>
__global__ __launch_bounds__(256)
void gemm_bt(const short* __restrict__ A, const short* __restrict__ B,
             int N, int K, int kchunk,
             short* __restrict__ outB, float* __restrict__ outF,
             const short* __restrict__ Xadd, const float* __restrict__ cates) {
    __shared__ __align__(16) char smem[(64 + 128) * 64 * 2];
    char* As = smem;                 // [64 rows][8 slots x16B], col16 XOR-swizzled by row&7
    char* Bs = smem + 64 * 64 * 2;   // [128 rows][8 slots x16B]
    const int tid = threadIdx.x;
    const int w = tid >> 6, lane = tid & 63;
    const int m0 = blockIdx.x * 64;
    const int n0 = blockIdx.y * 128;
    const int kstart = blockIdx.z * kchunk;
    const int wm = (w >> 1) * 32, wn = (w & 1) * 64;

    f32x4 acc[2][4];
    #pragma unroll
    for (int i = 0; i < 2; ++i)
        #pragma unroll
        for (int j = 0; j < 4; ++j) acc[i][j] = (f32x4){0.f, 0.f, 0.f, 0.f};

    const int nsteps = kchunk >> 6;
    for (int s = 0; s < nsteps; ++s) {
        int kpos = kstart + (s << 6);
        __syncthreads();
        #pragma unroll
        for (int gi = 0; gi < 6; ++gi) {
            int g = w * 6 + gi;
            if (g < 8) {
                int sl = g * 64 + lane;
                int row = sl >> 3, col = sl & 7;
                int sc = col ^ (row & 7);
                g2l16(A + (size_t)(m0 + row) * K + kpos + sc * 8, As + g * 1024);
            } else {
                int gb = g - 8;
                int sl = gb * 64 + lane;
                int row = sl >> 3, col = sl & 7;
                int sc = col ^ (row & 7);
                g2l16(B + (size_t)(n0 + row) * K + kpos + sc * 8, Bs + gb * 1024);
            }
        }
        __syncthreads();   // compiler drains vmcnt before barrier -> staged data visible
        #pragma unroll
        for (int kk = 0; kk < 2; ++kk) {
            bf16x8 af[2], bfr[4];
            #pragma unroll
            for (int mi = 0; mi < 2; ++mi) {
                int row = wm + mi * 16 + (lane & 15);
                int c16 = (kk * 4 + (lane >> 4)) ^ (row & 7);
                af[mi] = *(const bf16x8*)(As + row * 128 + c16 * 16);
            }
            #pragma unroll
            for (int ni = 0; ni < 4; ++ni) {
                int row = wn + ni * 16 + (lane & 15);
                int c16 = (kk * 4 + (lane >> 4)) ^ (row & 7);
                bfr[ni] = *(const bf16x8*)(Bs + row * 128 + c16 * 16);
            }
            #pragma unroll
            for (int mi = 0; mi < 2; ++mi)
                #pragma unroll
                for (int ni = 0; ni < 4; ++ni)
                    acc[mi][ni] = __builtin_amdgcn_mfma_f32_16x16x32_bf16(
                        af[mi], bfr[ni], acc[mi][ni], 0, 0, 0);
        }
    }

    #pragma unroll
    for (int mi = 0; mi < 2; ++mi) {
        #pragma unroll
        for (int ni = 0; ni < 4; ++ni) {
            int rg = m0 + wm + mi * 16 + (lane >> 4) * 4;
            int cg = n0 + wn + ni * 16 + (lane & 15);
            f32x4 a = acc[mi][ni];
            if (MODE == 0) {
                #pragma unroll
                for (int j = 0; j < 4; ++j)
                    outB[(size_t)(rg + j) * N + cg] = f2b(a[j]);
            } else if (MODE == 1) {
                #pragma unroll
                for (int j = 0; j < 4; ++j) {
                    float x = b2f(Xadd[(size_t)(rg + j) * N + cg]);
                    outB[(size_t)(rg + j) * N + cg] = f2b((a[j] + x) * 0.5f);
                }
            } else if (MODE == 2) {
                #pragma unroll
                for (int j = 0; j < 4; ++j)
                    atomicAdd(&outF[(size_t)(rg + j) * N + cg], a[j]);
            } else {
                const float4 c4 = *(const float4*)(cates + (size_t)cg * 4);
                float p = __expf(a[0]) * c4.x + __expf(a[1]) * c4.y +
                          __expf(a[2]) * c4.z + __expf(a[3]) * c4.w;
                outF[(size_t)(rg >> 2) * N + cg] = __logf(p);
            }
        }
    }
}

// ---------------- launch ----------------

extern "C" void kernel_launch(void* const* d_in, const int* in_sizes, int n_in,
                              void* d_out, int out_size, void* d_ws, size_t ws_size,
                              hipStream_t stream) {
    const float* x_cf    = (const float*)d_in[0];
    const float* x_txt   = (const float*)d_in[1];
    const float* adj     = (const float*)d_in[2];
    const float* cf_emb  = (const float*)d_in[3];
    const float* cf_proto= (const float*)d_in[4];
    const float* cf_W    = (const float*)d_in[5];
    const float* cf_bias = (const float*)d_in[6];
    const float* t_emb   = (const float*)d_in[7];
    const float* t_proto = (const float*)d_in[8];
    const float* t_W     = (const float*)d_in[9];
    const float* t_bias  = (const float*)d_in[10];
    float* out = (float*)d_out;
    char* ws = (char*)d_ws;

    // workspace layout (bytes)
    short* adjT  = (short*)(ws + 0);            // 8192*8192*2 = 134217728
    short* xkcf  = (short*)(ws + 134217728);    // 512*8192*2  = 8388608
    short* t1    = (short*)(ws + 142606336);    // 8388608
    short* xkn   = (short*)(ws + 150994944);    // 8388608
    short* xktxt = (short*)(ws + 159383552);    // 512*16384*2 = 16777216
    short* itcf  = (short*)(ws + 176160768);    // 8192*64*2   = 1048576
    short* ittxt = (short*)(ws + 177209344);    // 16384*64*2  = 2097152
    float* ccf   = (float*)(ws + 179306496);    // 8192*4*4    = 131072
    float* ctxt  = (float*)(ws + 179437568);    // 262144
    short* wcf   = (short*)(ws + 179699712);    // 128*8192*2  = 2097152
    short* wtxt  = (short*)(ws + 181796864);    // 4194304
    float* hcf   = (float*)(ws + 185991168);    // 512*128*4   = 262144
    float* htxt  = (float*)(ws + 186253312);    // 262144
    short* zcf   = (short*)(ws + 186515456);    // 65536
    short* ztxt  = (short*)(ws + 186580992);    // 65536

    float* out_rat = out;
    float* out_txt = out + 1048576;
    float* mu_cf   = out + 3145728;
    float* lv_cf   = out + 3178496;
    float* mu_t    = out + 3211264;
    float* lv_t    = out + 3244032;

    dim3 b256(256);
    f2b_kernel<<<dim3(4096), b256, 0, stream>>>(cf_W, wcf, 1048576);
    f2b_kernel<<<dim3(8192), b256, 0, stream>>>(t_W, wtxt, 2097152);
    items_cates<<<dim3(2048), b256, 0, stream>>>(cf_emb, cf_proto, itcf, ccf, 8192);
    items_cates<<<dim3(4096), b256, 0, stream>>>(t_emb, t_proto, ittxt, ctxt, 16384);
    xk_kernel<<<dim3(512), b256, 0, stream>>>(x_cf, ccf, xkcf, 8192);
    xk_kernel<<<dim3(512), b256, 0, stream>>>(x_txt, ctxt, xktxt, 16384);
    transpose_bf16<<<dim3(128, 128), b256, 0, stream>>>(adj, adjT, 8192);
    zerof<<<dim3(512), b256, 0, stream>>>(hcf, 131072);  // hcf+htxt contiguous

    // hop1: T1 = XK @ adj ; hop2: XKN = (T1 @ adj + XK)*0.5
    gemm_bt<0><<<dim3(8, 64, 1), b256, 0, stream>>>(xkcf, adjT, 8192, 8192, 8192,
                                                    t1, nullptr, nullptr, nullptr);
    gemm_bt<1><<<dim3(8, 64, 1), b256, 0, stream>>>(t1, adjT, 8192, 8192, 8192,
                                                    xkn, nullptr, xkcf, nullptr);
    // h = xk @ W^T (split-K, atomic f32)
    gemm_bt<2><<<dim3(8, 1, 32), b256, 0, stream>>>(xkn, wcf, 128, 8192, 256,
                                                    nullptr, hcf, nullptr, nullptr);
    gemm_bt<2><<<dim3(8, 1, 32), b256, 0, stream>>>(xktxt, wtxt, 128, 16384, 512,
                                                    nullptr, htxt, nullptr, nullptr);
    mu_logvar<<<dim3(1024), dim3(128), 0, stream>>>(hcf, htxt, cf_bias, t_bias,
                                                    mu_cf, lv_cf, mu_t, lv_t, zcf, ztxt);
    // decode: logits = log(sum_k exp(Z' @ items^T) * cates)
    gemm_bt<3><<<dim3(8, 64, 1), b256, 0, stream>>>(zcf, itcf, 8192, 64, 64,
                                                    nullptr, out_rat, nullptr, ccf);
    gemm_bt<3><<<dim3(8, 128, 1), b256, 0, stream>>>(ztxt, ittxt, 16384, 64, 64,
                                                     nullptr, out_txt, nullptr, ctxt);
}

// Round 6
// 798.692 us; speedup vs baseline: 1.1137x; 1.1137x over previous
//
#include <hip/hip_runtime.h>
#include <hip/hip_bf16.h>
#include <cstdint>

typedef __bf16 bf16x8 __attribute__((ext_vector_type(8)));
typedef float  f32x4  __attribute__((ext_vector_type(4)));

__device__ __forceinline__ short f2b(float f) {
    union { float f; uint32_t u; } c{f};
    uint32_t u = c.u;
    uint32_t r = (u + 0x7FFFu + ((u >> 16) & 1u)) >> 16;
    return (short)(uint16_t)r;
}
__device__ __forceinline__ float b2f(short s) {
    return __uint_as_float(((uint32_t)(uint16_t)s) << 16);
}
__device__ __forceinline__ float wred(float v) {
    #pragma unroll
    for (int o = 32; o > 0; o >>= 1) v += __shfl_xor(v, o);
    return v;
}
// async global->LDS, 16B per lane; lds dest must be wave-uniform base.
__device__ __forceinline__ void g2l16(const void* g, void* l) {
    __builtin_amdgcn_global_load_lds(
        (const __attribute__((address_space(1))) void*)(uintptr_t)g,
        (__attribute__((address_space(3))) void*)(uint32_t)(uintptr_t)l,
        16, 0, 0);
}

// ---------------- small prep kernels ----------------

__global__ __launch_bounds__(256) void f2b_kernel(const float* __restrict__ in,
                                                  short* __restrict__ out, int n) {
    int i = blockIdx.x * 256 + threadIdx.x;
    if (i < n) out[i] = f2b(in[i]);
}

__global__ __launch_bounds__(256) void zerof(float* __restrict__ p, int n) {
    int i = blockIdx.x * 256 + threadIdx.x;
    if (i < n) p[i] = 0.f;
}

// one wave per item row: normalize item, dot vs 4 normalized protos, softmax -> cates
__global__ __launch_bounds__(256)
void items_cates(const float* __restrict__ emb, const float* __restrict__ proto,
                 short* __restrict__ items_b, float* __restrict__ cates, int N) {
    int w = threadIdx.x >> 6, lane = threadIdx.x & 63;
    int n = blockIdx.x * 4 + w;
    if (n >= N) return;
    float p0 = proto[lane], p1 = proto[64 + lane], p2 = proto[128 + lane], p3 = proto[192 + lane];
    float s0 = wred(p0 * p0); p0 /= fmaxf(sqrtf(s0), 1e-12f);
    float s1 = wred(p1 * p1); p1 /= fmaxf(sqrtf(s1), 1e-12f);
    float s2 = wred(p2 * p2); p2 /= fmaxf(sqrtf(s2), 1e-12f);
    float s3 = wred(p3 * p3); p3 /= fmaxf(sqrtf(s3), 1e-12f);
    float x = emb[(size_t)n * 64 + lane];
    float sx = wred(x * x);
    float xi = x / fmaxf(sqrtf(sx), 1e-12f);
    items_b[(size_t)n * 64 + lane] = f2b(xi);
    float d0 = wred(xi * p0), d1 = wred(xi * p1), d2 = wred(xi * p2), d3 = wred(xi * p3);
    float m = fmaxf(fmaxf(d0, d1), fmaxf(d2, d3));
    float e0 = __expf(d0 - m), e1 = __expf(d1 - m), e2 = __expf(d2 - m), e3 = __expf(d3 - m);
    float inv = 1.0f / (e0 + e1 + e2 + e3);
    float cv = (lane == 0) ? e0 : (lane == 1) ? e1 : (lane == 2) ? e2 : e3;
    if (lane < 4) cates[(size_t)n * 4 + lane] = cv * inv;
}

// one block per (k,b) row: xk = l2norm_over_n(x[b,:]*cates[:,k]) -> bf16
__global__ __launch_bounds__(256)
void xk_kernel(const float* __restrict__ x, const float* __restrict__ cates,
               short* __restrict__ out, int N) {
    __shared__ float red[4];
    int kb = blockIdx.x, k = kb >> 7, b = kb & 127;
    int tid = threadIdx.x, w = tid >> 6, lane = tid & 63;
    const float* xr = x + (size_t)b * N;
    float ss = 0.f;
    for (int i = tid; i < N; i += 256) {
        float v = xr[i] * cates[(size_t)i * 4 + k];
        ss += v * v;
    }
    ss = wred(ss);
    if (lane == 0) red[w] = ss;
    __syncthreads();
    float tot = red[0] + red[1] + red[2] + red[3];
    float inv = 1.0f / fmaxf(sqrtf(tot), 1e-12f);
    for (int i = tid; i < N; i += 256)
        out[(size_t)kb * N + i] = f2b(xr[i] * cates[(size_t)i * 4 + k] * inv);
}

// AdjT[j][i] = Adj[i][j], fp32 -> bf16, 64x64 tiles through LDS.
// Write phase: 8 shorts gathered from LDS per thread -> one dwordx4 store.
__global__ __launch_bounds__(256)
void transpose_bf16(const float* __restrict__ A, short* __restrict__ At, int Nd) {
    __shared__ float t[64][65];
    int i0 = blockIdx.x * 64, j0 = blockIdx.y * 64;
    int tid = threadIdx.x;
    #pragma unroll
    for (int p = 0; p < 4; ++p) {
        int idx = p * 256 + tid;
        int r = idx >> 4, c4 = (idx & 15) * 4;
        const float4 v = *(const float4*)(A + (size_t)(i0 + r) * Nd + j0 + c4);
        t[r][c4] = v.x; t[r][c4 + 1] = v.y; t[r][c4 + 2] = v.z; t[r][c4 + 3] = v.w;
    }
    __syncthreads();
    #pragma unroll
    for (int p = 0; p < 2; ++p) {
        int idx = p * 256 + tid;
        int r = idx >> 3, c0 = (idx & 7) * 8;     // out-row r, col block c0
        uint32_t d[4];
        #pragma unroll
        for (int q = 0; q < 4; ++q) {
            uint32_t lo = (uint32_t)(uint16_t)f2b(t[c0 + 2 * q][r]);
            uint32_t hi = (uint32_t)(uint16_t)f2b(t[c0 + 2 * q + 1][r]);
            d[q] = lo | (hi << 16);
        }
        *(uint4*)(At + (size_t)(j0 + r) * Nd + i0 + c0) =
            make_uint4(d[0], d[1], d[2], d[3]);
    }
}

// mu = l2norm(h[:64]+b), logvar = -(h[64:]+b); also write Z'[(b*4+k)][e] bf16 for decode
__global__ __launch_bounds__(128)
void mu_logvar(const float* __restrict__ hcf, const float* __restrict__ htxt,
               const float* __restrict__ bcf, const float* __restrict__ btxt,
               float* __restrict__ mu_cf, float* __restrict__ lv_cf,
               float* __restrict__ mu_t, float* __restrict__ lv_t,
               short* __restrict__ zcf, short* __restrict__ ztxt) {
    int r = blockIdx.x & 511;
    bool txt = blockIdx.x >= 512;
    const float* h = txt ? htxt : hcf;
    const float* bias = txt ? btxt : bcf;
    float* muo = txt ? mu_t : mu_cf;
    float* lvo = txt ? lv_t : lv_cf;
    short* z = txt ? ztxt : zcf;
    int t = threadIdx.x;
    float v = h[(size_t)r * 128 + t] + bias[t];
    if (t < 64) {
        float ss = wred(v * v);
        float mu = v / fmaxf(sqrtf(ss), 1e-12f);
        muo[(size_t)r * 64 + t] = mu;
        int k = r >> 7, b = r & 127;
        z[((size_t)b * 4 + k) * 64 + t] = f2b(mu);
    } else {
        lvo[(size_t)r * 64 + (t - 64)] = -v;
    }
}

// ---------------- BT-GEMM: C[m][n] = sum_k A[m][k]*B[n][k], bf16 MFMA ----------------
// BM=64, BN=128, BK=64; 4 waves (2x2), each 32x64 (2x4 fragments of 16x16x32).
// 2-phase double-buffered LDS: prefetch tile s+1 (12x global_load_lds) issued
// BEFORE ds_read+MFMA of tile s; single __syncthreads per K-step (T3-minimum).
// NOTE (R5 fix): slab row index must use g for A and g-8 for B (B has 16 slabs;
// the R4 "(g&7)" collapse aliased B rows 64..127 onto 0..63 -> absmax 0.73).
// SWZ=1: XCD swizzle (8 m-sharers of one B-panel -> same XCD L2).
// MODE 0: store bf16. MODE 1: store bf16 of (acc+X)*0.5. MODE 2: atomicAdd f32 (split-K).
// MODE 3: decode epilogue: rows are b*4+k; out[b][n] = log(sum_j exp(acc[j])*cates[n][j]).
template <int MODE, int SWZ>
__global__ __launch_bounds__(256)
void gemm_bt(const short* __restrict__ A, const short* __restrict__ B,
             int N, int K, int kchunk,
             short* __restrict__ outB, float* __restrict__ outF,
             const short* __restrict__ Xadd, const float* __restrict__ cates) {
    __shared__ __align__(16) char smem[2][(64 + 128) * 64 * 2];
    const int tid = threadIdx.x;
    const int w = tid >> 6, lane = tid & 63;
    int bx = blockIdx.x, by = blockIdx.y;
    if (SWZ) {   // 512 blocks, gridDim.x==8: XCD x gets 8 consecutive n-panels
        int flat = by * 8 + bx;
        int work = (flat & 7) * 64 + (flat >> 3);
        bx = work & 7; by = work >> 3;
    }
    const int m0 = bx * 64;
    const int n0 = by * 128;
    const int kstart = blockIdx.z * kchunk;
    const int wm = (w >> 1) * 32, wn = (w & 1) * 64;

    auto stage = [&](int buf, int kpos) {
        char* As = smem[buf];
        char* Bs = smem[buf] + 64 * 64 * 2;
        #pragma unroll
        for (int gi = 0; gi < 6; ++gi) {
            int g = w * 6 + gi;
            if (g < 8) {
                int sl = g * 64 + lane;
                int row = sl >> 3, col = sl & 7;
                int sc = col ^ (row & 7);
                g2l16(A + (size_t)(m0 + row) * K + kpos + sc * 8, As + g * 1024);
            } else {
                int gb = g - 8;
                int sl = gb * 64 + lane;
                int row = sl >> 3, col = sl & 7;
                int sc = col ^ (row & 7);
                g2l16(B + (size_t)(n0 + row) * K + kpos + sc * 8, Bs + gb * 1024);
            }
        }
    };

    f32x4 acc[2][4];
    #pragma unroll
    for (int i = 0; i < 2; ++i)
        #pragma unroll
        for (int j = 0; j < 4; ++j) acc[i][j] = (f32x4){0.f, 0.f, 0.f, 0.f};

    const int nsteps = kchunk >> 6;
    stage(0, kstart);
    __syncthreads();
    int cur = 0;
    for (int s = 0; s < nsteps; ++s) {
        if (s + 1 < nsteps) stage(cur ^ 1, kstart + ((s + 1) << 6));
        const char* As = smem[cur];
        const char* Bs = smem[cur] + 64 * 64 * 2;
        #pragma unroll
        for (int kk = 0; kk < 2; ++kk) {
            bf16x8 af[2], bfr[4];
            #pragma unroll
            for (int mi = 0; mi < 2; ++mi) {
                int row = wm + mi * 16 + (lane & 15);
                int c16 = (kk * 4 + (lane >> 4)) ^ (row & 7);
                af[mi] = *(const bf16x8*)(As + row * 128 + c16 * 16);
            }
            #pragma unroll
            for (int ni = 0; ni < 4; ++ni) {
                int row = wn + ni * 16 + (lane & 15);
                int c16 = (kk * 4 + (lane >> 4)) ^ (row & 7);
                bfr[ni] = *(const bf16x8*)(Bs + row * 128 + c16 * 16);
            }
            #pragma unroll
            for (int mi = 0; mi < 2; ++mi)
                #pragma unroll
                for (int ni = 0; ni < 4; ++ni)
                    acc[mi][ni] = __builtin_amdgcn_mfma_f32_16x16x32_bf16(
                        af[mi], bfr[ni], acc[mi][ni], 0, 0, 0);
        }
        __syncthreads();   // drains vmcnt (prefetch) + lgkmcnt; one barrier per step
        cur ^= 1;
    }

    #pragma unroll
    for (int mi = 0; mi < 2; ++mi) {
        #pragma unroll
        for (int ni = 0; ni < 4; ++ni) {
            int rg = m0 + wm + mi * 16 + (lane >> 4) * 4;
            int cg = n0 + wn + ni * 16 + (lane & 15);
            f32x4 a = acc[mi][ni];
            if (MODE == 0) {
                #pragma unroll
                for (int j = 0; j < 4; ++j)
                    outB[(size_t)(rg + j) * N + cg] = f2b(a[j]);
            } else if (MODE == 1) {
                #pragma unroll
                for (int j = 0; j < 4; ++j) {
                    float x = b2f(Xadd[(size_t)(rg + j) * N + cg]);
                    outB[(size_t)(rg + j) * N + cg] = f2b((a[j] + x) * 0.5f);
                }
            } else if (MODE == 2) {
                #pragma unroll
                for (int j = 0; j < 4; ++j)
                    atomicAdd(&outF[(size_t)(rg + j) * N + cg], a[j]);
            } else {
                const float4 c4 = *(const float4*)(cates + (size_t)cg * 4);
                float p = __expf(a[0]) * c4.x + __expf(a[1]) * c4.y +
                          __expf(a[2]) * c4.z + __expf(a[3]) * c4.w;
                outF[(size_t)(rg >> 2) * N + cg] = __logf(p);
            }
        }
    }
}

// ---------------- launch ----------------

extern "C" void kernel_launch(void* const* d_in, const int* in_sizes, int n_in,
                              void* d_out, int out_size, void* d_ws, size_t ws_size,
                              hipStream_t stream) {
    const float* x_cf    = (const float*)d_in[0];
    const float* x_txt   = (const float*)d_in[1];
    const float* adj     = (const float*)d_in[2];
    const float* cf_emb  = (const float*)d_in[3];
    const float* cf_proto= (const float*)d_in[4];
    const float* cf_W    = (const float*)d_in[5];
    const float* cf_bias = (const float*)d_in[6];
    const float* t_emb   = (const float*)d_in[7];
    const float* t_proto = (const float*)d_in[8];
    const float* t_W     = (const float*)d_in[9];
    const float* t_bias  = (const float*)d_in[10];
    float* out = (float*)d_out;
    char* ws = (char*)d_ws;

    // workspace layout (bytes)
    short* adjT  = (short*)(ws + 0);            // 8192*8192*2 = 134217728
    short* xkcf  = (short*)(ws + 134217728);    // 512*8192*2  = 8388608
    short* t1    = (short*)(ws + 142606336);    // 8388608
    short* xkn   = (short*)(ws + 150994944);    // 8388608
    short* xktxt = (short*)(ws + 159383552);    // 512*16384*2 = 16777216
    short* itcf  = (short*)(ws + 176160768);    // 8192*64*2   = 1048576
    short* ittxt = (short*)(ws + 177209344);    // 16384*64*2  = 2097152
    float* ccf   = (float*)(ws + 179306496);    // 8192*4*4    = 131072
    float* ctxt  = (float*)(ws + 179437568);    // 262144
    short* wcf   = (short*)(ws + 179699712);    // 128*8192*2  = 2097152
    short* wtxt  = (short*)(ws + 181796864);    // 4194304
    float* hcf   = (float*)(ws + 185991168);    // 512*128*4   = 262144
    float* htxt  = (float*)(ws + 186253312);    // 262144
    short* zcf   = (short*)(ws + 186515456);    // 65536
    short* ztxt  = (short*)(ws + 186580992);    // 65536

    float* out_rat = out;
    float* out_txt = out + 1048576;
    float* mu_cf   = out + 3145728;
    float* lv_cf   = out + 3178496;
    float* mu_t    = out + 3211264;
    float* lv_t    = out + 3244032;

    dim3 b256(256);
    f2b_kernel<<<dim3(4096), b256, 0, stream>>>(cf_W, wcf, 1048576);
    f2b_kernel<<<dim3(8192), b256, 0, stream>>>(t_W, wtxt, 2097152);
    items_cates<<<dim3(2048), b256, 0, stream>>>(cf_emb, cf_proto, itcf, ccf, 8192);
    items_cates<<<dim3(4096), b256, 0, stream>>>(t_emb, t_proto, ittxt, ctxt, 16384);
    xk_kernel<<<dim3(512), b256, 0, stream>>>(x_cf, ccf, xkcf, 8192);
    xk_kernel<<<dim3(512), b256, 0, stream>>>(x_txt, ctxt, xktxt, 16384);
    transpose_bf16<<<dim3(128, 128), b256, 0, stream>>>(adj, adjT, 8192);
    zerof<<<dim3(512), b256, 0, stream>>>(hcf, 131072);  // hcf+htxt contiguous

    // hop1: T1 = XK @ adj ; hop2: XKN = (T1 @ adj + XK)*0.5
    gemm_bt<0, 1><<<dim3(8, 64, 1), b256, 0, stream>>>(xkcf, adjT, 8192, 8192, 8192,
                                                       t1, nullptr, nullptr, nullptr);
    gemm_bt<1, 1><<<dim3(8, 64, 1), b256, 0, stream>>>(t1, adjT, 8192, 8192, 8192,
                                                       xkn, nullptr, xkcf, nullptr);
    // h = xk @ W^T (split-K, atomic f32)
    gemm_bt<2, 0><<<dim3(8, 1, 32), b256, 0, stream>>>(xkn, wcf, 128, 8192, 256,
                                                       nullptr, hcf, nullptr, nullptr);
    gemm_bt<2, 0><<<dim3(8, 1, 32), b256, 0, stream>>>(xktxt, wtxt, 128, 16384, 512,
                                                       nullptr, htxt, nullptr, nullptr);
    mu_logvar<<<dim3(1024), dim3(128), 0, stream>>>(hcf, htxt, cf_bias, t_bias,
                                                    mu_cf, lv_cf, mu_t, lv_t, zcf, ztxt);
    // decode: logits = log(sum_k exp(Z' @ items^T) * cates)
    gemm_bt<3, 0><<<dim3(8, 64, 1), b256, 0, stream>>>(zcf, itcf, 8192, 64, 64,
                                                       nullptr, out_rat, nullptr, ccf);
    gemm_bt<3, 0><<<dim3(8, 128, 1), b256, 0, stream>>>(ztxt, ittxt, 16384, 64, 64,
                                                        nullptr, out_txt, nullptr, ctxt);
}